// Round 3
// baseline (150.030 us; speedup 1.0000x reference)
//
#include <hip/hip_runtime.h>
#include <hip/hip_bf16.h>

// Problem constants: N=4096, D=512, H=256, O=256, M=8, K=2, F=512, C=2
#define N_TOK 4096
#define D_IN  512
#define H_DIM 256
#define O_DIM 256
#define M_EXP 8
#define F_DIM 512

typedef __attribute__((ext_vector_type(8))) short bf16x8;   // 8 bf16 = 4 VGPRs (MFMA A/B frag)
typedef __attribute__((ext_vector_type(4))) float f32x4;    // MFMA C/D frag

// RNE f32 -> bf16 bits
__device__ __forceinline__ unsigned short f2bf(float f) {
    unsigned int u = __float_as_uint(f);
    u = (u + 0x7FFFu + ((u >> 16) & 1u)) >> 16;
    return (unsigned short)u;
}

// async global->LDS, 16B per lane; LDS dest = wave-uniform base + lane*16
__device__ __forceinline__ void gload_lds16(const void* g, void* l) {
    __builtin_amdgcn_global_load_lds(
        (const __attribute__((address_space(1))) unsigned int*)g,
        (__attribute__((address_space(3))) unsigned int*)l, 16, 0, 0);
}

// Swizzled LDS byte offsets. Tiles with 64B rows (4x16B slots): slot ^= (row>>1)&3.
__device__ __forceinline__ int sw64(int row, int lslot) {
    return row * 64 + ((lslot ^ ((row >> 1) & 3)) << 4);
}
// Hs tile: 512B rows (32x16B slots): slot ^= row&7.
__device__ __forceinline__ int swHs(int row, int lslot) {
    return row * 512 + ((lslot ^ (row & 7)) << 4);
}

// ---------------------------------------------------------------------------
// Gating (f32-exact; reduction order identical to round-1/2 so top-k never
// flips) + X f32->bf16 conversion fused (Xbf[2][4096][512]).
// ---------------------------------------------------------------------------
__global__ __launch_bounds__(256) void gate_kernel(
    const float* __restrict__ Xb, const float* __restrict__ Xc,
    const float* __restrict__ Wg, const float* __restrict__ bg,
    float* __restrict__ coef_b, float* __restrict__ coef_c,
    float* __restrict__ mask_b, float* __restrict__ mask_c,
    float* __restrict__ gsum, float* __restrict__ cnt,
    unsigned short* __restrict__ Xbf)
{
    const int mod = blockIdx.y;
    const float* X = mod ? Xc : Xb;
    float* coef = mod ? coef_c : coef_b;
    float* mask = mod ? mask_c : mask_b;
    const int wave = threadIdx.x >> 6;
    const int lane = threadIdx.x & 63;
    const int n = blockIdx.x * 4 + wave;

    __shared__ float s_g[M_EXP];
    __shared__ float s_c[M_EXP];
    if (threadIdx.x < M_EXP) { s_g[threadIdx.x] = 0.f; s_c[threadIdx.x] = 0.f; }
    __syncthreads();

    float acc[M_EXP] = {0.f,0.f,0.f,0.f,0.f,0.f,0.f,0.f};
    const float* xrow = X + (size_t)n * D_IN;
    unsigned short* xb = Xbf + (size_t)mod * N_TOK * D_IN + (size_t)n * D_IN;
#pragma unroll
    for (int k = 0; k < 8; ++k) {
        const int d = lane + 64 * k;
        const float xv = xrow[d];
        xb[d] = f2bf(xv);
        const float* wr = Wg + d * M_EXP;
#pragma unroll
        for (int m = 0; m < M_EXP; ++m) acc[m] += xv * wr[m];
    }
#pragma unroll
    for (int off = 1; off < 64; off <<= 1) {
#pragma unroll
        for (int m = 0; m < M_EXP; ++m) acc[m] += __shfl_xor(acc[m], off, 64);
    }
    float g[M_EXP];
    float mx = -1e30f;
#pragma unroll
    for (int m = 0; m < M_EXP; ++m) { g[m] = acc[m] + bg[m]; mx = fmaxf(mx, g[m]); }
    float es = 0.f;
#pragma unroll
    for (int m = 0; m < M_EXP; ++m) { g[m] = expf(g[m] - mx); es += g[m]; }
    const float inv = 1.f / es;
#pragma unroll
    for (int m = 0; m < M_EXP; ++m) g[m] *= inv;

    int i0 = 0; float v0 = g[0];
#pragma unroll
    for (int m = 1; m < M_EXP; ++m) if (g[m] > v0) { v0 = g[m]; i0 = m; }
    int i1 = -1; float v1 = -1e30f;
#pragma unroll
    for (int m = 0; m < M_EXP; ++m) if (m != i0 && g[m] > v1) { v1 = g[m]; i1 = m; }

    if (lane == 0) {
        const float wn = 1.f / (v0 + v1);
        coef[i0 * N_TOK + n] = v0 * wn;
        coef[i1 * N_TOK + n] = v1 * wn;
        mask[i0 * N_TOK + n] = 1.f;
        mask[i1 * N_TOK + n] = 1.f;
#pragma unroll
        for (int m = 0; m < M_EXP; ++m) atomicAdd(&s_g[m], g[m]);
        atomicAdd(&s_c[i0], 1.f);
        atomicAdd(&s_c[i1], 1.f);
    }
    __syncthreads();
    if (threadIdx.x < M_EXP) {
        atomicAdd(&gsum[mod * M_EXP + threadIdx.x], s_g[threadIdx.x]);
        atomicAdd(&cnt[mod * M_EXP + threadIdx.x], s_c[threadIdx.x]);
    }
}

// ---------------------------------------------------------------------------
// Merged prep: W1 transpose (blocks [0,1024)), W2 transpose ([1024,1536)),
// Wf fold+transpose ([1536,1792)), out init with bc ([1792,1824)).
// ---------------------------------------------------------------------------
__global__ __launch_bounds__(256) void prep_kernel(
    const float* __restrict__ W1, const float* __restrict__ W2,
    const float* __restrict__ Wf, const float* __restrict__ bc,
    unsigned short* __restrict__ W1T, unsigned short* __restrict__ W2T,
    unsigned short* __restrict__ WfT, float* __restrict__ out)
{
    __shared__ float tile[32][33];
    const int bx = blockIdx.x;
    const int tr = threadIdx.x >> 3, q = threadIdx.x & 7;
    if (bx < 1024) {            // W1 [8][512][256] -> W1T [8][256][512]
        const int e = bx >> 7, tidx = bx & 127;
        const int r0 = (tidx >> 3) * 32, c0 = (tidx & 7) * 32;
        const float* s = W1 + (size_t)e * 512 * 256;
        unsigned short* d = W1T + (size_t)e * 512 * 256;
        *(float4*)&tile[tr][q * 4] = *(const float4*)&s[(size_t)(r0 + tr) * 256 + c0 + q * 4];
        __syncthreads();
        ushort4 o;
        o.x = f2bf(tile[q*4+0][tr]); o.y = f2bf(tile[q*4+1][tr]);
        o.z = f2bf(tile[q*4+2][tr]); o.w = f2bf(tile[q*4+3][tr]);
        *(ushort4*)&d[(size_t)(c0 + tr) * 512 + r0 + q * 4] = o;
    } else if (bx < 1536) {     // W2 [8][256][256] -> W2T [8][256][256]
        const int idx = bx - 1024;
        const int e = idx >> 6, tidx = idx & 63;
        const int r0 = (tidx >> 3) * 32, c0 = (tidx & 7) * 32;
        const float* s = W2 + (size_t)e * 256 * 256;
        unsigned short* d = W2T + (size_t)e * 256 * 256;
        *(float4*)&tile[tr][q * 4] = *(const float4*)&s[(size_t)(r0 + tr) * 256 + c0 + q * 4];
        __syncthreads();
        ushort4 o;
        o.x = f2bf(tile[q*4+0][tr]); o.y = f2bf(tile[q*4+1][tr]);
        o.z = f2bf(tile[q*4+2][tr]); o.w = f2bf(tile[q*4+3][tr]);
        *(ushort4*)&d[(size_t)(c0 + tr) * 256 + r0 + q * 4] = o;
    } else if (bx < 1792) {     // WfT_eff[f][j] = Wf[j][f] + (j>=256 ? Wf[j+256][f] : 0)
        const int idx = bx - 1536;
        const int j0 = (idx >> 4) * 32, f0 = (idx & 15) * 32;
        float4 v = *(const float4*)&Wf[(size_t)(j0 + tr) * F_DIM + f0 + q * 4];
        if (j0 >= 256) {
            const float4 v2 = *(const float4*)&Wf[(size_t)(j0 + tr + 256) * F_DIM + f0 + q * 4];
            v.x += v2.x; v.y += v2.y; v.z += v2.z; v.w += v2.w;
        }
        *(float4*)&tile[tr][q * 4] = v;
        __syncthreads();
        ushort4 o;
        o.x = f2bf(tile[q*4+0][tr]); o.y = f2bf(tile[q*4+1][tr]);
        o.z = f2bf(tile[q*4+2][tr]); o.w = f2bf(tile[q*4+3][tr]);
        *(ushort4*)&WfT[(size_t)(f0 + tr) * 512 + j0 + q * 4] = o;
    } else {                    // out init
        const int i = (bx - 1792) * 256 + threadIdx.x;
        out[i] = bc[i & 1];
    }
}

// ---------------------------------------------------------------------------
// Expert MLPs via MFMA, 2-phase pipelined. Grid (64 token-tiles, 2mod x 4eg).
// Each block: 2 experts on a 64-token tile. BM=64, BN=256, BK=32, 4 waves.
// Double-buffered Xs/Ws (global_load_lds, pre-swizzled source); Hs in LDS.
// Pipeline: stage(chunk c+1) -> ds_read+MFMA(chunk c) -> syncthreads.
// ---------------------------------------------------------------------------
__global__ __launch_bounds__(256, 2) void expert_mfma_kernel(
    const unsigned short* __restrict__ Xbf,
    const unsigned short* __restrict__ W1T, const unsigned short* __restrict__ W2T,
    const float* __restrict__ b1, const float* __restrict__ b2,
    const float* __restrict__ coef_b, const float* __restrict__ coef_c,
    const float* __restrict__ mask_b, const float* __restrict__ mask_c,
    float* __restrict__ out_b, float* __restrict__ out_c,
    float* __restrict__ sum_out)
{
    __shared__ __align__(16) char Xs[2][4096];    // [64 rows][32 bf16] x2
    __shared__ __align__(16) char Ws[2][16384];   // [256 rows][32 bf16] x2
    __shared__ __align__(16) char Hs[32768];      // [64 rows][256 bf16]

    const int t = threadIdx.x;
    const int w = t >> 6, l = t & 63;
    const int lr = l & 15, lk = l >> 4;
    const int mod = blockIdx.y >> 2, eg = blockIdx.y & 3;
    const float* coef = mod ? coef_c : coef_b;
    const float* mask = mod ? mask_c : mask_b;
    float* outp = mod ? out_c : out_b;
    const float modw = mod ? 2.f : 1.f;
    const int base = blockIdx.x * 64;
    const int wcol = w * 64;

    // X staging source (pre-swizzled per-lane global address; LDS dest linear)
    const int xrow = t >> 2;
    const int xls  = (t & 3) ^ ((xrow >> 1) & 3);
    const unsigned short* xsrc =
        Xbf + (size_t)mod * N_TOK * D_IN + (size_t)(base + xrow) * D_IN + xls * 8;
    // W staging geometry
    const int wrow_l = l >> 2;
    const int wp = l & 3;

    auto stage_x = [&](int kc, int buf) {
        gload_lds16(xsrc + kc * 32, &Xs[buf][t * 16]);
    };
    auto stage_w = [&](const unsigned short* wbase, int rowlen, int kc, int buf) {
#pragma unroll
        for (int s2 = 0; s2 < 4; ++s2) {
            const int row = w * 64 + s2 * 16 + wrow_l;
            const int lslot = wp ^ ((row >> 1) & 3);
            gload_lds16(wbase + (size_t)row * rowlen + kc * 32 + lslot * 8,
                        &Ws[buf][w * 4096 + s2 * 1024]);
        }
    };

    f32x4 acc[4][4];
    f32x4 oacc[4][4];
#pragma unroll
    for (int mi = 0; mi < 4; ++mi)
#pragma unroll
        for (int nj = 0; nj < 4; ++nj) { f32x4 z = {0.f,0.f,0.f,0.f}; oacc[mi][nj] = z; }
    unsigned active = 0;

    int buf = 0;
    stage_x(0, 0);
    stage_w(W1T + (size_t)(eg * 2) * H_DIM * D_IN, 512, 0, 0);
    __syncthreads();

    for (int e = 0; e < 2; ++e) {
        const int m = eg * 2 + e;
        const unsigned short* w1p = W1T + (size_t)m * H_DIM * D_IN;
        const unsigned short* w2p = W2T + (size_t)m * O_DIM * H_DIM;

        // ---------------- h phase: 16 chunks of K=32 ----------------
#pragma unroll
        for (int nj = 0; nj < 4; ++nj) {
            const float bv = b1[m * H_DIM + wcol + nj * 16 + lr];
#pragma unroll
            for (int mi = 0; mi < 4; ++mi) { f32x4 z = {bv,bv,bv,bv}; acc[mi][nj] = z; }
        }
        for (int kc = 0; kc < 16; ++kc) {
            const int nb = buf ^ 1;
            if (kc < 15) { stage_x(kc + 1, nb); stage_w(w1p, 512, kc + 1, nb); }
            else         { stage_w(w2p, 256, 0, nb); }
            bf16x8 a[4], b[4];
#pragma unroll
            for (int mi = 0; mi < 4; ++mi)
                a[mi] = *(const bf16x8*)&Xs[buf][sw64(mi * 16 + lr, lk)];
#pragma unroll
            for (int nj = 0; nj < 4; ++nj)
                b[nj] = *(const bf16x8*)&Ws[buf][sw64(wcol + nj * 16 + lr, lk)];
#pragma unroll
            for (int mi = 0; mi < 4; ++mi)
#pragma unroll
                for (int nj = 0; nj < 4; ++nj)
                    acc[mi][nj] = __builtin_amdgcn_mfma_f32_16x16x32_bf16(a[mi], b[nj], acc[mi][nj], 0, 0, 0);
            if (kc == 15) {
                // relu -> Hs (bf16, swizzled)
#pragma unroll
                for (int mi = 0; mi < 4; ++mi)
#pragma unroll
                    for (int nj = 0; nj < 4; ++nj) {
                        const int col = wcol + nj * 16 + lr;
                        const int cslot = col >> 3;
                        const int cbyte = (col & 7) * 2;
#pragma unroll
                        for (int j = 0; j < 4; ++j) {
                            const int row = mi * 16 + lk * 4 + j;
                            *(unsigned short*)&Hs[row * 512 + ((cslot ^ (row & 7)) << 4) + cbyte] =
                                f2bf(fmaxf(acc[mi][nj][j], 0.f));
                        }
                    }
            }
            __syncthreads();
            buf = nb;
        }

        // ---------------- y phase: 8 chunks of K=32 ----------------
#pragma unroll
        for (int nj = 0; nj < 4; ++nj) {
            const float bv = b2[m * O_DIM + wcol + nj * 16 + lr];
#pragma unroll
            for (int mi = 0; mi < 4; ++mi) { f32x4 z = {bv,bv,bv,bv}; acc[mi][nj] = z; }
        }
        for (int kc = 0; kc < 8; ++kc) {
            const int nb = buf ^ 1;
            if (kc < 7)      stage_w(w2p, 256, kc + 1, nb);
            else if (e == 0) { stage_x(0, nb); stage_w(w1p + (size_t)H_DIM * D_IN, 512, 0, nb); }
            bf16x8 a[4], b[4];
#pragma unroll
            for (int mi = 0; mi < 4; ++mi)
                a[mi] = *(const bf16x8*)&Hs[swHs(mi * 16 + lr, kc * 4 + lk)];
#pragma unroll
            for (int nj = 0; nj < 4; ++nj)
                b[nj] = *(const bf16x8*)&Ws[buf][sw64(wcol + nj * 16 + lr, lk)];
#pragma unroll
            for (int mi = 0; mi < 4; ++mi)
#pragma unroll
                for (int nj = 0; nj < 4; ++nj)
                    acc[mi][nj] = __builtin_amdgcn_mfma_f32_16x16x32_bf16(a[mi], b[nj], acc[mi][nj], 0, 0, 0);
            __syncthreads();
            buf = nb;
        }

        // ---------------- per-expert epilogue (register/LDS only) ----------------
        float sacc[4] = {0.f, 0.f, 0.f, 0.f};
#pragma unroll
        for (int mi = 0; mi < 4; ++mi)
#pragma unroll
            for (int j = 0; j < 4; ++j) {
                const int lrow = mi * 16 + lk * 4 + j;
                const float cf = coef[(size_t)m * N_TOK + base + lrow];
                const float mk = mask[(size_t)m * N_TOK + base + lrow];
                if (cf != 0.f) active |= 1u << (mi * 4 + j);
#pragma unroll
                for (int nj = 0; nj < 4; ++nj) {
                    const float v = acc[mi][nj][j];
                    oacc[mi][nj][j] = fmaf(cf, v, oacc[mi][nj][j]);
                    sacc[nj] = fmaf(mk, v, sacc[nj]);
                }
            }
#pragma unroll
        for (int nj = 0; nj < 4; ++nj) {
            sacc[nj] += __shfl_xor(sacc[nj], 16, 64);
            sacc[nj] += __shfl_xor(sacc[nj], 32, 64);
        }
        if (lk == 0) {
#pragma unroll
            for (int nj = 0; nj < 4; ++nj)
                atomicAdd(&sum_out[m * O_DIM + wcol + nj * 16 + lr], sacc[nj] * modw);
        }
    }

    // ---------------- final combine write (predicated atomics) ----------------
#pragma unroll
    for (int mi = 0; mi < 4; ++mi)
#pragma unroll
        for (int j = 0; j < 4; ++j) {
            if ((active >> (mi * 4 + j)) & 1) {
                const size_t grow = (size_t)(base + mi * 16 + lk * 4 + j) * O_DIM;
#pragma unroll
                for (int nj = 0; nj < 4; ++nj)
                    atomicAdd(&outp[grow + wcol + nj * 16 + lr], oacc[mi][nj][j]);
            }
        }
}

// ---------------------------------------------------------------------------
// Fusion + classifier, fused (unchanged from round 2).
// ---------------------------------------------------------------------------
__global__ __launch_bounds__(256, 4) void fuse_cls_kernel(
    const float* __restrict__ out_b, const float* __restrict__ out_c,
    const unsigned short* __restrict__ WfT, const float* __restrict__ bf,
    const float* __restrict__ Wc, float* __restrict__ out)
{
    __shared__ __align__(16) char As[32 * 64];
    __shared__ __align__(16) char Ws[256 * 64];
    const int t = threadIdx.x;
    const int w = t >> 6;
    const int l = t & 63;
    const int lr = l & 15, lk = l >> 4;
    const int base = blockIdx.x * 32;
    const int half = blockIdx.y;
    const int colbase = half * 256 + w * 64;

    f32x4 acc[2][4] = {};

    const int arow = t >> 2;
    const int aslot = (t & 3) ^ ((arow >> 1) & 3);
    const int wrow_l = l >> 2;
    const int wpslot = l & 3;

    for (int kc = 0; kc < 16; ++kc) {
        __syncthreads();
        if (t < 128) {
            const int gk = kc * 32 + aslot * 8;
            const float* src = (gk < 256 ? out_b : out_c) + (size_t)(base + arow) * 256 + (gk & 255);
            const float4 f0 = *(const float4*)src;
            const float4 f1 = *(const float4*)(src + 4);
            bf16x8 p;
            p[0] = (short)f2bf(f0.x); p[1] = (short)f2bf(f0.y);
            p[2] = (short)f2bf(f0.z); p[3] = (short)f2bf(f0.w);
            p[4] = (short)f2bf(f1.x); p[5] = (short)f2bf(f1.y);
            p[6] = (short)f2bf(f1.z); p[7] = (short)f2bf(f1.w);
            *(bf16x8*)&As[t * 16] = p;
        }
#pragma unroll
        for (int s2 = 0; s2 < 4; ++s2) {
            const int row = w * 64 + s2 * 16 + wrow_l;
            const int lslot = wpslot ^ ((row >> 1) & 3);
            gload_lds16(WfT + (size_t)(half * 256 + row) * 512 + kc * 32 + lslot * 8,
                        &Ws[w * 4096 + s2 * 1024]);
        }
        __syncthreads();
        bf16x8 a[2], b[4];
#pragma unroll
        for (int mi = 0; mi < 2; ++mi)
            a[mi] = *(const bf16x8*)&As[sw64(mi * 16 + lr, lk)];
#pragma unroll
        for (int nj = 0; nj < 4; ++nj)
            b[nj] = *(const bf16x8*)&Ws[sw64(w * 64 + nj * 16 + lr, lk)];
#pragma unroll
        for (int mi = 0; mi < 2; ++mi)
#pragma unroll
            for (int nj = 0; nj < 4; ++nj)
                acc[mi][nj] = __builtin_amdgcn_mfma_f32_16x16x32_bf16(a[mi], b[nj], acc[mi][nj], 0, 0, 0);
    }

#pragma unroll
    for (int mi = 0; mi < 2; ++mi)
#pragma unroll
        for (int j = 0; j < 4; ++j) {
            float p0 = 0.f, p1 = 0.f;
#pragma unroll
            for (int nj = 0; nj < 4; ++nj) {
                const int col = colbase + nj * 16 + lr;
                const float r = fmaxf(acc[mi][nj][j] + bf[col], 0.f);
                p0 = fmaf(r, Wc[col * 2 + 0], p0);
                p1 = fmaf(r, Wc[col * 2 + 1], p1);
            }
#pragma unroll
            for (int off = 1; off < 16; off <<= 1) {
                p0 += __shfl_xor(p0, off, 64);
                p1 += __shfl_xor(p1, off, 64);
            }
            if (lr == 0) {
                const int row = base + mi * 16 + lk * 4 + j;
                atomicAdd(&out[row * 2 + 0], p0);
                atomicAdd(&out[row * 2 + 1], p1);
            }
        }
}

// ---------------------------------------------------------------------------
// Losses (unchanged).
// ---------------------------------------------------------------------------
__global__ __launch_bounds__(256) void loss_kernel(
    const float* __restrict__ gsum, const float* __restrict__ cnt,
    const float* __restrict__ sum_out, float* __restrict__ dout)
{
    __shared__ float avg[M_EXP][O_DIM];
    __shared__ float rho_s[M_EXP];
    __shared__ float simv[28];
    __shared__ float prs[28];
    const int t = threadIdx.x;
    if (t < M_EXP) rho_s[t] = cnt[t] + 2.f * cnt[M_EXP + t];
    __syncthreads();
    for (int idx = t; idx < M_EXP * O_DIM; idx += 256) {
        const int m = idx >> 8;
        avg[m][idx & 255] = sum_out[idx] / fmaxf(rho_s[m], 1.f);
    }
    __syncthreads();
    if (t < 28) {
        int a = 0, p = t;
        while (p >= 7 - a) { p -= 7 - a; ++a; }
        const int b = a + 1 + p;
        float d2 = 0.f;
        for (int o = 0; o < O_DIM; ++o) {
            const float df = avg[a][o] - avg[b][o];
            d2 = fmaf(df, df, d2);
        }
        const bool pr = (rho_s[a] > 0.f) && (rho_s[b] > 0.f);
        simv[t] = pr ? expf(-0.5f * d2) : 0.f;
        prs[t]  = pr ? 1.f : 0.f;
    }
    __syncthreads();
    if (t == 0) {
        float s = 0.f, np = 0.f;
        for (int p = 0; p < 28; ++p) { s += simv[p]; np += prs[p]; }
        dout[N_TOK * 2 + 0] = -s / fmaxf(np, 1.f);
        float eq = 0.f;
        for (int m = 0; m < M_EXP; ++m) {
            const float rho = cnt[m] + 2.f * cnt[M_EXP + m];
            const float rh  = gsum[m] + 2.f * gsum[M_EXP + m];
            eq = fmaf(rho, rh, eq);
        }
        dout[N_TOK * 2 + 1] = eq / (float)M_EXP;
    }
}

// ---------------------------------------------------------------------------
extern "C" void kernel_launch(void* const* d_in, const int* in_sizes, int n_in,
                              void* d_out, int out_size, void* d_ws, size_t ws_size,
                              hipStream_t stream)
{
    const float* Xb = (const float*)d_in[0];
    const float* Xc = (const float*)d_in[1];
    // d_in[2] (vec_fcg) intentionally unused: reference source bug reuses cfg.
    const float* Wg = (const float*)d_in[3];
    const float* bg = (const float*)d_in[4];
    const float* W1 = (const float*)d_in[5];
    const float* b1 = (const float*)d_in[6];
    const float* W2 = (const float*)d_in[7];
    const float* b2 = (const float*)d_in[8];
    const float* Wf = (const float*)d_in[9];
    const float* bf = (const float*)d_in[10];
    const float* Wc = (const float*)d_in[11];
    const float* bc = (const float*)d_in[12];
    float* out = (float*)d_out;

    float* ws = (float*)d_ws;
    float* coef_b  = ws;                           // 32768
    float* coef_c  = coef_b + M_EXP * N_TOK;
    float* mask_b  = coef_c + M_EXP * N_TOK;
    float* mask_c  = mask_b + M_EXP * N_TOK;
    float* gsum    = mask_c + M_EXP * N_TOK;       // [2][8]
    float* cnt     = gsum + 16;                    // [2][8]
    float* sum_out = cnt + 16;                     // [8][256]
    float* out_b   = sum_out + M_EXP * O_DIM;      // [4096][256] f32 (atomic)
    float* out_c   = out_b + (size_t)N_TOK * O_DIM;
    unsigned short* W1T = (unsigned short*)(out_c + (size_t)N_TOK * O_DIM); // [8][256][512]
    unsigned short* W2T = W1T + (size_t)M_EXP * H_DIM * D_IN;              // [8][256][256]
    unsigned short* WfT = W2T + (size_t)M_EXP * O_DIM * H_DIM;             // [512][512]
    unsigned short* Xbf = WfT + (size_t)F_DIM * 512;                       // [2][4096][512]

    // zero atomic-accumulated regions (coef..sum_out + out_b + out_c)
    const size_t zero_f = (size_t)(4 * M_EXP * N_TOK + 32 + M_EXP * O_DIM) + 2 * (size_t)N_TOK * O_DIM;
    hipMemsetAsync(d_ws, 0, zero_f * sizeof(float), stream);

    prep_kernel<<<dim3(1824), 256, 0, stream>>>(W1, W2, Wf, bc, W1T, W2T, WfT, out);
    gate_kernel<<<dim3(N_TOK / 4, 2), 256, 0, stream>>>(
        Xb, Xc, Wg, bg, coef_b, coef_c, mask_b, mask_c, gsum, cnt, Xbf);
    expert_mfma_kernel<<<dim3(N_TOK / 64, 8), 256, 0, stream>>>(
        Xbf, W1T, W2T, b1, b2, coef_b, coef_c, mask_b, mask_c, out_b, out_c, sum_out);
    fuse_cls_kernel<<<dim3(N_TOK / 32, 2), 256, 0, stream>>>(out_b, out_c, WfT, bf, Wc, out);
    loss_kernel<<<1, 256, 0, stream>>>(gsum, cnt, sum_out, out);
}